// Round 8
// baseline (884.666 us; speedup 1.0000x reference)
//
#include <hip/hip_runtime.h>

#define NN 50000
#define NE 800000
#define HD 128
#define NSL 128          // edge slices
#define SLE (NE / NSL)   // 6250 edges per slice
#define PW  12500        // packed words per chunk (2 bins/word, 25000 bins/chunk)

typedef __attribute__((ext_vector_type(8))) short short8;
typedef __attribute__((ext_vector_type(4))) float f32x4;
typedef __attribute__((ext_vector_type(2))) int i32x2;
typedef __attribute__((ext_vector_type(4))) unsigned u32x4;

__device__ inline unsigned bf2pack(float lo, float hi) {
    unsigned a = __float_as_uint(lo); a = (a + 0x7fffu + ((a >> 16) & 1u)) >> 16;
    unsigned b = __float_as_uint(hi); b = (b + 0x7fffu + ((b >> 16) & 1u)) >> 16;
    return a | (b << 16);
}

// ---------------------------------------------------------------------------
// Graph prep (atomic-free)
// ---------------------------------------------------------------------------
__global__ __launch_bounds__(256) void k_hist(const int* __restrict__ ei,
                                              unsigned* __restrict__ phist) {
    __shared__ unsigned hist[PW];  // 50 KB
    int b = blockIdx.x;
    int a = b >> 8;
    int s = (b & 255) >> 1;
    int c = b & 1;
    int tid = threadIdx.x;
    for (int i = tid; i < PW; i += 256) hist[i] = 0u;
    __syncthreads();
    const int* arr = ei + a * NE + s * SLE;
    int lo = c * 25000;
    for (int i = tid; i < SLE; i += 256) {
        int v = arr[i] - lo;
        if ((unsigned)v < 25000u)
            atomicAdd(&hist[v >> 1], 1u << ((v & 1) * 16));
    }
    __syncthreads();
    unsigned* dst = phist + (size_t)b * PW;
    for (int i = tid; i < PW; i += 256) dst[i] = hist[i];
}

__global__ __launch_bounds__(256) void k_hreduce(const unsigned* __restrict__ phist,
                                                 float* __restrict__ dinv,
                                                 int* __restrict__ cnt,
                                                 unsigned* __restrict__ pre) {
    int idx = blockIdx.x * 256 + threadIdx.x;
    if (idx >= 50000) return;
    int a = idx / 25000;
    int gw = idx % 25000;
    int c = gw / PW;
    int w = gw % PW;
    unsigned accLo = 0, accHi = 0;
    for (int s = 0; s < NSL; s++) {
        unsigned p = phist[(size_t)(((a * NSL + s) * 2 + c)) * PW + w];
        if (a == 1) pre[(size_t)s * 25000 + gw] = accLo | (accHi << 16);
        accLo += p & 0xffffu;
        accHi += p >> 16;
    }
    int b0 = c * 25000 + 2 * w;
    if (a == 0) {
        dinv[b0]     = accLo ? rsqrtf((float)accLo) : 0.0f;
        dinv[b0 + 1] = accHi ? rsqrtf((float)accHi) : 0.0f;
    } else {
        cnt[b0]     = (int)accLo;
        cnt[b0 + 1] = (int)accHi;
    }
}

__global__ __launch_bounds__(1024) void k_scan1(const int* __restrict__ cnt,
                                                int* __restrict__ rowptr,
                                                int* __restrict__ bsum) {
    __shared__ int s[1024];
    int tid = threadIdx.x;
    int gid = blockIdx.x * 1024 + tid;
    int v = (gid < NN) ? cnt[gid] : 0;
    s[tid] = v;
    __syncthreads();
    for (int off = 1; off < 1024; off <<= 1) {
        int t = 0;
        if (tid >= off) t = s[tid - off];
        __syncthreads();
        s[tid] += t;
        __syncthreads();
    }
    if (gid < NN) rowptr[gid] = s[tid] - v;
    if (tid == 1023) bsum[blockIdx.x] = s[1023];
}

__global__ void k_scan2(const int* __restrict__ bsum, int* __restrict__ boff,
                        int nb, int* __restrict__ rowptr) {
    if (threadIdx.x == 0 && blockIdx.x == 0) {
        int acc = 0;
        for (int i = 0; i < nb; i++) { boff[i] = acc; acc += bsum[i]; }
        rowptr[NN] = acc;
    }
}

__global__ void k_scan3(int* __restrict__ rowptr, const int* __restrict__ boff) {
    int i = blockIdx.x * 256 + threadIdx.x;
    if (i < NN) rowptr[i] += boff[i >> 10];
}

__global__ __launch_bounds__(256) void k_fill2(const int* __restrict__ ei,
                                               const float* __restrict__ dinv,
                                               const int* __restrict__ rowptr,
                                               const unsigned* __restrict__ pre,
                                               int2* __restrict__ edg) {
    __shared__ unsigned rank[PW];  // 50 KB
    int b = blockIdx.x;
    int s = b >> 1;
    int c = b & 1;
    int tid = threadIdx.x;
    for (int i = tid; i < PW; i += 256) rank[i] = 0u;
    __syncthreads();
    int lo = c * 25000;
    const unsigned* preS = pre + (size_t)s * 25000 + c * PW;
    for (int i = tid; i < SLE; i += 256) {
        int e = s * SLE + i;
        int d = ei[NE + e];
        int v = d - lo;
        if ((unsigned)v < 25000u) {
            int src = ei[e];
            int w = v >> 1;
            int sh = (v & 1) * 16;
            unsigned r = atomicAdd(&rank[w], 1u << sh);
            r = (r >> sh) & 0xffffu;
            unsigned pw = (preS[w] >> sh) & 0xffffu;
            int pos = rowptr[d] + (int)pw + (int)r;
            edg[pos] = make_int2(src, __float_as_int(-dinv[src] * dinv[d]));
        }
    }
}

// ---------------------------------------------------------------------------
// Degree-grouped node permutation: counting sort by in-degree (64 bins).
// Atomic-free across blocks (LDS hist -> transposed partials -> scan -> scatter)
// ---------------------------------------------------------------------------
__global__ __launch_bounds__(256) void k_dhist(const int* __restrict__ cnt,
                                               unsigned* __restrict__ dph) {
    __shared__ unsigned h[64];
    int b = blockIdx.x, t = threadIdx.x;
    if (t < 64) h[t] = 0u;
    __syncthreads();
    int n0 = b * 196, n1 = n0 + 196;
    if (n1 > NN) n1 = NN;
    for (int n = n0 + t; n < n1; n += 256) {
        int d = cnt[n];
        int bin = d > 63 ? 63 : d;
        atomicAdd(&h[bin], 1u);
    }
    __syncthreads();
    if (t < 64) dph[t * 256 + b] = h[t];   // transposed: [bin][block]
}

__global__ __launch_bounds__(1024) void k_dscan(const unsigned* __restrict__ dph,
                                                unsigned* __restrict__ gofs) {
    __shared__ unsigned ps[1024];
    int t = threadIdx.x;
    unsigned v[16];
    unsigned s = 0;
    #pragma unroll
    for (int i = 0; i < 16; i++) {
        unsigned x = dph[t * 16 + i];
        v[i] = s;            // exclusive-local
        s += x;
    }
    ps[t] = s;
    __syncthreads();
    for (int off = 1; off < 1024; off <<= 1) {
        unsigned x = 0;
        if (t >= off) x = ps[t - off];
        __syncthreads();
        ps[t] += x;
        __syncthreads();
    }
    unsigned pref = (t == 0) ? 0u : ps[t - 1];
    #pragma unroll
    for (int i = 0; i < 16; i++) gofs[t * 16 + i] = v[i] + pref;
}

__global__ __launch_bounds__(256) void k_dscatter(const int* __restrict__ cnt,
                                                  const unsigned* __restrict__ gofs,
                                                  int* __restrict__ perm) {
    __shared__ unsigned h[64];
    int b = blockIdx.x, t = threadIdx.x;
    if (t < 64) h[t] = 0u;
    __syncthreads();
    int n0 = b * 196, n1 = n0 + 196;
    if (n1 > NN) n1 = NN;
    for (int n = n0 + t; n < n1; n += 256) {
        int d = cnt[n];
        int bin = d > 63 ? 63 : d;
        unsigned r = atomicAdd(&h[bin], 1u);
        perm[gofs[bin * 256 + b] + r] = n;
    }
}

// ---------------------------------------------------------------------------
// Propagation dim-3 (fp32, layer 1 only), degree-grouped via perm
// ---------------------------------------------------------------------------
__global__ void k_prop3(const float* __restrict__ h, const float* __restrict__ sub,
                        const int* __restrict__ rowptr, const int2* __restrict__ edg,
                        const int* __restrict__ perm, float* __restrict__ out) {
    int slot = blockIdx.x * 256 + threadIdx.x;
    if (slot >= NN) return;
    int node = perm[slot];
    int e0 = rowptr[node], e1 = rowptr[node + 1];
    float a0 = 0.f, a1 = 0.f, a2 = 0.f;
    for (int e = e0; e < e1; e++) {
        int2 p = edg[e];
        int s = p.x;
        float v = __int_as_float(p.y);
        a0 += v * h[s * 3 + 0];
        a1 += v * h[s * 3 + 1];
        a2 += v * h[s * 3 + 2];
    }
    if (sub) {
        a0 = 2.f * a0 - sub[node * 3 + 0];
        a1 = 2.f * a1 - sub[node * 3 + 1];
        a2 = 2.f * a2 - sub[node * 3 + 2];
    }
    out[node * 3 + 0] = a0;
    out[node * 3 + 1] = a1;
    out[node * 3 + 2] = a2;
}

// ---------------------------------------------------------------------------
// Propagation dim-128, feature-planar bf16 [plane 0..3][node][32].
// XCD-pinned chunks; shfl-shared edge loads; DEGREE-GROUPED nodes via perm
// (all 16 nodes in a wave have ~equal degree -> no tail divergence).
// ---------------------------------------------------------------------------
#define ACC8(acc, u, v)                                               \
    acc[0] = fmaf(v, __uint_as_float(u[0] << 16), acc[0]);            \
    acc[1] = fmaf(v, __uint_as_float(u[0] & 0xffff0000u), acc[1]);    \
    acc[2] = fmaf(v, __uint_as_float(u[1] << 16), acc[2]);            \
    acc[3] = fmaf(v, __uint_as_float(u[1] & 0xffff0000u), acc[3]);    \
    acc[4] = fmaf(v, __uint_as_float(u[2] << 16), acc[4]);            \
    acc[5] = fmaf(v, __uint_as_float(u[2] & 0xffff0000u), acc[5]);    \
    acc[6] = fmaf(v, __uint_as_float(u[3] << 16), acc[6]);            \
    acc[7] = fmaf(v, __uint_as_float(u[3] & 0xffff0000u), acc[7]);

__global__ __launch_bounds__(256) void k_prop_pl(
        const unsigned short* __restrict__ h, const unsigned short* __restrict__ sub,
        const int* __restrict__ rowptr, const int2* __restrict__ edg,
        const int* __restrict__ perm, unsigned short* __restrict__ out) {
    int B = blockIdx.x;
    int xcd = B & 7;
    int c = xcd >> 1;        // chunk pinned to XCD pair
    int half = xcd & 1;      // node-range half
    int g = B >> 3;          // 0..391
    int slot = (half * 392 + g) * 64 + (threadIdx.x >> 2);
    if (slot >= NN) return;
    int n = perm[slot];
    int lane4 = threadIdx.x & 3;
    int sl = lane4 * 8;                       // ushort slice offset
    int base = (threadIdx.x & 63) & ~3;       // node's first lane in wave
    const unsigned short* hp = h + (size_t)c * (NN * 32);
    int e0 = rowptr[n], e1 = rowptr[n + 1];
    float a[8] = {0, 0, 0, 0, 0, 0, 0, 0};
    float b[8] = {0, 0, 0, 0, 0, 0, 0, 0};
    int e = e0;
    for (; e + 4 <= e1; e += 4) {
        i32x2 p = __builtin_nontemporal_load((const i32x2*)(edg + e + lane4));
        int s0 = __shfl(p[0], base + 0, 64);
        int s1 = __shfl(p[0], base + 1, 64);
        int s2 = __shfl(p[0], base + 2, 64);
        int s3 = __shfl(p[0], base + 3, 64);
        float v0 = __int_as_float(__shfl(p[1], base + 0, 64));
        float v1 = __int_as_float(__shfl(p[1], base + 1, 64));
        float v2 = __int_as_float(__shfl(p[1], base + 2, 64));
        float v3 = __int_as_float(__shfl(p[1], base + 3, 64));
        u32x4 u0 = *(const u32x4*)(hp + s0 * 32 + sl);
        u32x4 u1 = *(const u32x4*)(hp + s1 * 32 + sl);
        u32x4 u2 = *(const u32x4*)(hp + s2 * 32 + sl);
        u32x4 u3 = *(const u32x4*)(hp + s3 * 32 + sl);
        ACC8(a, u0, v0)
        ACC8(b, u1, v1)
        ACC8(a, u2, v2)
        ACC8(b, u3, v3)
    }
    for (; e < e1; e++) {
        i32x2 p = __builtin_nontemporal_load((const i32x2*)(edg + e));
        u32x4 u = *(const u32x4*)(hp + p[0] * 32 + sl);
        float v = __int_as_float(p[1]);
        ACC8(a, u, v)
    }
    float r[8];
    #pragma unroll
    for (int q = 0; q < 8; q++) r[q] = a[q] + b[q];
    if (sub) {
        u32x4 su = __builtin_nontemporal_load(
            (const u32x4*)(sub + (size_t)c * (NN * 32) + n * 32 + sl));
        float s[8];
        s[0] = __uint_as_float(su[0] << 16); s[1] = __uint_as_float(su[0] & 0xffff0000u);
        s[2] = __uint_as_float(su[1] << 16); s[3] = __uint_as_float(su[1] & 0xffff0000u);
        s[4] = __uint_as_float(su[2] << 16); s[5] = __uint_as_float(su[2] & 0xffff0000u);
        s[6] = __uint_as_float(su[3] << 16); s[7] = __uint_as_float(su[3] & 0xffff0000u);
        #pragma unroll
        for (int q = 0; q < 8; q++) r[q] = 2.f * r[q] - s[q];
    }
    u32x4 o;
    o[0] = bf2pack(r[0], r[1]);
    o[1] = bf2pack(r[2], r[3]);
    o[2] = bf2pack(r[4], r[5]);
    o[3] = bf2pack(r[6], r[7]);
    __builtin_nontemporal_store(o, (u32x4*)(out + (size_t)c * (NN * 32) + n * 32 + sl));
}

// ---------------------------------------------------------------------------
// W swizzle fp32 -> bf16 B-fragment order for all three 128x128 weights.
// ---------------------------------------------------------------------------
__global__ void k_wconv_all(const float* __restrict__ W2, const float* __restrict__ W3,
                            const float* __restrict__ W4, unsigned short* __restrict__ Wb) {
    int gidx = blockIdx.x * 256 + threadIdx.x;  // 0..196607
    int which = gidx >> 16;
    int idx = gidx & 65535;
    const float* W = which == 0 ? W2 : (which == 1 ? W3 : W4);
    int slot = idx >> 9;
    int lane = (idx >> 3) & 63;
    int j = idx & 7;
    int wg = slot >> 4;
    int t = slot & 15;
    int w = wg >> 1;
    int g = wg & 1;
    int k = t * 32 + (lane >> 4) * 8 + j;
    int col = w * 32 + g * 16 + (lane & 15);
    unsigned u = __float_as_uint(W[k * HD + col]);
    Wb[which * 65536 + idx] = (unsigned short)((u + 0x7fffu + ((u >> 16) & 1u)) >> 16);
}

// ---------------------------------------------------------------------------
// MFMA GEMM. A staged per 16-row tile into LDS (fragment order); B register-
// resident. Fused BN partials written NON-ATOMICALLY to gpart[col][512].
// ---------------------------------------------------------------------------
__global__ __launch_bounds__(256) void k_gemmM(
        const unsigned short* __restrict__ A0, const unsigned short* __restrict__ A1,
        const unsigned short* __restrict__ A2, const unsigned short* __restrict__ A3,
        const unsigned short* __restrict__ Wb, const float* __restrict__ bias,
        float* __restrict__ outF, int act, float* __restrict__ gpart) {
    __shared__ unsigned short Asm[16 * 64 * 8];  // 16 KB
    const int tid = threadIdx.x;
    const int w = tid >> 6;
    const int lane = tid & 63;
    const int l15 = lane & 15;
    const int quad = lane >> 4;

    short8 Bf[16][2];
    #pragma unroll
    for (int t = 0; t < 16; t++) {
        #pragma unroll
        for (int g = 0; g < 2; g++) {
            int slot = (w * 2 + g) * 16 + t;
            Bf[t][g] = *(const short8*)(Wb + slot * 512 + lane * 8);
        }
    }
    float bcol[2];
    bcol[0] = bias[w * 32 + l15];
    bcol[1] = bias[w * 32 + 16 + l15];

    const unsigned short* Ap[4] = {A0, A1, A2, A3};
    float bnP[2] = {0.f, 0.f}, bnQ[2] = {0.f, 0.f};

    for (int tile = blockIdx.x; tile < NN / 16; tile += gridDim.x) {
        int r0 = tile * 16;
        __syncthreads();
        #pragma unroll
        for (int i = 0; i < 4; i++) {
            int idx = i * 256 + tid;          // 0..1023
            int s = idx >> 6;                 // frag slot 0..15
            int ln = idx & 63;
            const unsigned short* src = Ap[s >> 2] + (size_t)(s & 3) * (NN * 32)
                                        + (r0 + (ln & 15)) * 32 + (ln >> 4) * 8;
            *(uint4*)&Asm[idx * 8] = *(const uint4*)src;
        }
        __syncthreads();
        f32x4 acc0 = {0.f, 0.f, 0.f, 0.f};
        f32x4 acc1 = {0.f, 0.f, 0.f, 0.f};
        #pragma unroll
        for (int s = 0; s < 16; s++) {
            short8 af = *(const short8*)&Asm[(s * 64 + lane) * 8];
            acc0 = __builtin_amdgcn_mfma_f32_16x16x32_bf16(af, Bf[s][0], acc0, 0, 0, 0);
            acc1 = __builtin_amdgcn_mfma_f32_16x16x32_bf16(af, Bf[s][1], acc1, 0, 0, 0);
        }
        #pragma unroll
        for (int reg = 0; reg < 4; reg++) {
            int row = r0 + quad * 4 + reg;
            float v0 = acc0[reg] + bcol[0];
            float v1 = acc1[reg] + bcol[1];
            if (act == 1) {
                v0 = v0 > 0.f ? v0 : 0.01f * v0;
                v1 = v1 > 0.f ? v1 : 0.01f * v1;
            } else if (act == 2) {
                v0 = v0 > 0.f ? v0 : 0.f;
                v1 = v1 > 0.f ? v1 : 0.f;
            }
            outF[row * HD + w * 32 + l15] = v0;
            outF[row * HD + w * 32 + 16 + l15] = v1;
            bnP[0] += v0; bnQ[0] += v0 * v0;
            bnP[1] += v1; bnQ[1] += v1 * v1;
        }
    }
    if (gpart) {
        #pragma unroll
        for (int g = 0; g < 2; g++) {
            float p = bnP[g], q = bnQ[g];
            p += __shfl_xor(p, 16); p += __shfl_xor(p, 32);
            q += __shfl_xor(q, 16); q += __shfl_xor(q, 32);
            if (quad == 0) {
                int col = w * 32 + g * 16 + l15;
                gpart[col * 512 + blockIdx.x] = p;
                gpart[(128 + col) * 512 + blockIdx.x] = q;
            }
        }
    }
}

// ---------------------------------------------------------------------------
// Layer-1 GEMM: [N,3] x4 Cheb terms @ W1[4][3][128] + b, leaky relu -> fp32
// ---------------------------------------------------------------------------
__global__ __launch_bounds__(256) void k_gemm1(
        const float* __restrict__ T0, const float* __restrict__ T1,
        const float* __restrict__ T2, const float* __restrict__ T3,
        const float* __restrict__ W, const float* __restrict__ bias,
        float* __restrict__ out) {
    __shared__ float Ws[12 * 128];
    __shared__ float tx[2][12];
    int t = threadIdx.x;
    for (int i = t; i < 12 * 128; i += 256) Ws[i] = W[i];
    int idx = blockIdx.x * 256 + t;
    int node = idx >> 7;
    int f = idx & 127;
    int localn = t >> 7;
    const float* Ts[4] = {T0, T1, T2, T3};
    if (f < 12 && node < NN) {
        tx[localn][f] = Ts[f / 3][node * 3 + (f % 3)];
    }
    __syncthreads();
    if (node < NN) {
        float acc = bias[f];
        #pragma unroll
        for (int c = 0; c < 12; c++) acc = fmaf(tx[localn][c], Ws[c * 128 + f], acc);
        acc = acc > 0.f ? acc : 0.01f * acc;
        out[node * HD + f] = acc;
    }
}

// ---------------------------------------------------------------------------
// BatchNorm: non-atomic two-stage reduction (stage 2 fused with finalize)
// ---------------------------------------------------------------------------
__global__ __launch_bounds__(256) void k_bnstats2(const float* __restrict__ h,
                                                  float* __restrict__ gpart) {
    __shared__ float red[512];
    int b = blockIdx.x;                 // 0..511
    int f = threadIdx.x & 127;
    int half = threadIdx.x >> 7;
    int r0 = b * 98 + half;
    int r1 = b * 98 + 98;
    if (r1 > NN) r1 = NN;
    float s = 0.f, q = 0.f;
    for (int r = r0; r < r1; r += 2) {
        float v = __builtin_nontemporal_load(h + r * HD + f);
        s += v;
        q += v * v;
    }
    red[threadIdx.x] = s;
    red[256 + threadIdx.x] = q;
    __syncthreads();
    if (threadIdx.x < 128) {
        gpart[f * 512 + b] = red[threadIdx.x] + red[threadIdx.x + 128];
        gpart[(128 + f) * 512 + b] = red[256 + threadIdx.x] + red[384 + threadIdx.x];
    }
}

__global__ __launch_bounds__(128) void k_bnredfin(const float* __restrict__ gpart,
                                                  const float* __restrict__ g,
                                                  const float* __restrict__ be,
                                                  float* __restrict__ ss) {
    __shared__ float sm[2];
    int f = blockIdx.x;            // 0..127
    int wave = threadIdx.x >> 6;   // 0: sum, 1: sumsq
    int lane = threadIdx.x & 63;
    const float* src = gpart + (size_t)(f + wave * 128) * 512;
    float s = 0.f;
    #pragma unroll
    for (int i = 0; i < 8; i++) s += src[i * 64 + lane];
    #pragma unroll
    for (int off = 32; off > 0; off >>= 1) s += __shfl_xor(s, off);
    if (lane == 0) sm[wave] = s;
    __syncthreads();
    if (threadIdx.x == 0) {
        float mean = sm[0] * (1.0f / NN);
        float var = sm[1] * (1.0f / NN) - mean * mean;
        float sc = g[f] * rsqrtf(var + 1e-5f);
        ss[f] = sc;
        ss[128 + f] = be[f] - mean * sc;
    }
}

// BN apply on fp32 row-major src -> bf16 feature-planar out
__global__ void k_bncvt_pl(const float* __restrict__ h, const float* __restrict__ ss,
                           unsigned short* __restrict__ out) {
    int idx = blockIdx.x * 256 + threadIdx.x;  // over NN*16 chunks of 8 feats
    if (idx < NN * 16) {
        int n = idx >> 4;
        int p = (idx >> 2) & 3;
        int q = idx & 3;
        const float4* hf = (const float4*)h;
        float4 v0 = hf[n * 32 + p * 8 + q * 2];
        float4 v1 = hf[n * 32 + p * 8 + q * 2 + 1];
        const float4* s4 = (const float4*)ss;
        float4 c0 = s4[p * 8 + q * 2];
        float4 c1 = s4[p * 8 + q * 2 + 1];
        float4 d0 = s4[32 + p * 8 + q * 2];
        float4 d1 = s4[32 + p * 8 + q * 2 + 1];
        v0.x = fmaf(v0.x, c0.x, d0.x); v0.y = fmaf(v0.y, c0.y, d0.y);
        v0.z = fmaf(v0.z, c0.z, d0.z); v0.w = fmaf(v0.w, c0.w, d0.w);
        v1.x = fmaf(v1.x, c1.x, d1.x); v1.y = fmaf(v1.y, c1.y, d1.y);
        v1.z = fmaf(v1.z, c1.z, d1.z); v1.w = fmaf(v1.w, c1.w, d1.w);
        uint4 o;
        o.x = bf2pack(v0.x, v0.y);
        o.y = bf2pack(v0.z, v0.w);
        o.z = bf2pack(v1.x, v1.y);
        o.w = bf2pack(v1.z, v1.w);
        ((uint4*)out)[(size_t)p * (NN * 4) + n * 4 + q] = o;
    }
}

// ---------------------------------------------------------------------------
// Row L2 normalize -> d_out
// ---------------------------------------------------------------------------
__global__ __launch_bounds__(256) void k_l2norm(const float* __restrict__ h,
                                                float* __restrict__ out) {
    int row = blockIdx.x * 4 + (threadIdx.x >> 6);
    int lane = threadIdx.x & 63;
    if (row >= NN) return;
    float2 v = *(const float2*)(h + row * HD + lane * 2);
    float s = v.x * v.x + v.y * v.y;
    #pragma unroll
    for (int off = 32; off > 0; off >>= 1) s += __shfl_xor(s, off);
    float scale = 1.f / fmaxf(sqrtf(s), 1e-12f);
    *(float2*)(out + row * HD + lane * 2) = make_float2(v.x * scale, v.y * scale);
}

// ---------------------------------------------------------------------------
// Launch
// ---------------------------------------------------------------------------
extern "C" void kernel_launch(void* const* d_in, const int* in_sizes, int n_in,
                              void* d_out, int out_size, void* d_ws, size_t ws_size,
                              hipStream_t stream) {
    const float* x  = (const float*)d_in[0];
    const int*   ei = (const int*)d_in[1];
    const float* W1 = (const float*)d_in[2];
    const float* b1 = (const float*)d_in[3];
    const float* W2 = (const float*)d_in[4];
    const float* b2 = (const float*)d_in[5];
    const float* W3 = (const float*)d_in[6];
    const float* b3 = (const float*)d_in[7];
    const float* W4 = (const float*)d_in[8];
    const float* b4 = (const float*)d_in[9];
    const float* g1 = (const float*)d_in[10];
    const float* be1 = (const float*)d_in[11];
    const float* g2 = (const float*)d_in[12];
    const float* be2 = (const float*)d_in[13];
    const float* g3 = (const float*)d_in[14];
    const float* be3 = (const float*)d_in[15];
    float* outp = (float*)d_out;

    char* base = (char*)d_ws;
    size_t off = 0;
    auto alloc = [&](size_t bytes) -> void* {
        void* p = base + off;
        off += (bytes + 255) & ~(size_t)255;
        return p;
    };
    float* dinv  = (float*)alloc(NN * 4);
    int*   cnt   = (int*)  alloc(NN * 4);
    int*   rowptr= (int*)  alloc((NN + 1) * 4);
    int*   bsum  = (int*)  alloc(64 * 4);
    int*   boff  = (int*)  alloc(64 * 4);
    float* ss    = (float*)alloc(256 * 4);
    float* gpart = (float*)alloc(256 * 512 * 4);
    unsigned* dph  = (unsigned*)alloc(64 * 256 * 4);
    unsigned* gofs = (unsigned*)alloc(64 * 256 * 4);
    int*   perm  = (int*)  alloc(NN * 4);
    unsigned short* Wb = (unsigned short*)alloc(3 * 512 * 128 * 2);
    int2*  edg   = (int2*) alloc((size_t)NE * 8);
    float* T3a   = (float*)alloc(NN * 3 * 4);
    float* T3b   = (float*)alloc(NN * 3 * 4);
    float* T3c   = (float*)alloc(NN * 3 * 4);
    float* F0    = (float*)alloc((size_t)NN * HD * 4);
    unsigned short* Bb0 = (unsigned short*)alloc((size_t)NN * HD * 2);
    unsigned short* Bb1 = (unsigned short*)alloc((size_t)NN * HD * 2);
    unsigned short* Bb2 = (unsigned short*)alloc((size_t)NN * HD * 2);
    unsigned short* Bb3 = (unsigned short*)alloc((size_t)NN * HD * 2);

    // overlays (consumed before their host slabs are first written):
    unsigned* pre   = (unsigned*)F0;    // 12.8 MB, freed by k_fill2
    unsigned* phist = (unsigned*)Bb0;   // 25.6 MB (Bb0+Bb1), freed by k_hreduce

    const int gN = (NN + 255) / 256;
    const int nb = (NN + 1023) / 1024;

    // ---- graph prep (no global atomics) ----
    k_hist<<<512, 256, 0, stream>>>(ei, phist);
    k_hreduce<<<(50000 + 255) / 256, 256, 0, stream>>>(phist, dinv, cnt, pre);
    k_scan1<<<nb, 1024, 0, stream>>>(cnt, rowptr, bsum);
    k_scan2<<<1, 64, 0, stream>>>(bsum, boff, nb, rowptr);
    k_scan3<<<gN, 256, 0, stream>>>(rowptr, boff);
    k_fill2<<<256, 256, 0, stream>>>(ei, dinv, rowptr, pre, edg);
    k_dhist<<<256, 256, 0, stream>>>(cnt, dph);
    k_dscan<<<1, 1024, 0, stream>>>(dph, gofs);
    k_dscatter<<<256, 256, 0, stream>>>(cnt, gofs, perm);
    k_wconv_all<<<768, 256, 0, stream>>>(W2, W3, W4, Wb);

    const int gPP = 8 * 392;         // XCD-pinned planar prop
    const int gG = 512;              // gemmM grid-stride blocks
    const int gCvt = NN * 16 / 256;  // 3125
    const int gL2 = (NN + 3) / 4;
    unsigned short* Wb2 = Wb;
    unsigned short* Wb3 = Wb + 65536;
    unsigned short* Wb4 = Wb + 131072;

    // ---- layer 1 (in: x [N,3], fp32) ----
    k_prop3<<<gN, 256, 0, stream>>>(x, nullptr, rowptr, edg, perm, T3a);
    k_prop3<<<gN, 256, 0, stream>>>(T3a, x, rowptr, edg, perm, T3b);
    k_prop3<<<gN, 256, 0, stream>>>(T3b, T3a, rowptr, edg, perm, T3c);
    k_gemm1<<<(NN * 128 + 255) / 256, 256, 0, stream>>>(x, T3a, T3b, T3c, W1, b1, F0);
    k_bnstats2<<<512, 256, 0, stream>>>(F0, gpart);
    k_bnredfin<<<128, 128, 0, stream>>>(gpart, g1, be1, ss);
    k_bncvt_pl<<<gCvt, 256, 0, stream>>>(F0, ss, Bb0);

    // ---- layer 2 ----
    k_prop_pl<<<gPP, 256, 0, stream>>>(Bb0, nullptr, rowptr, edg, perm, Bb1);
    k_prop_pl<<<gPP, 256, 0, stream>>>(Bb1, Bb0, rowptr, edg, perm, Bb2);
    k_prop_pl<<<gPP, 256, 0, stream>>>(Bb2, Bb1, rowptr, edg, perm, Bb3);
    k_gemmM<<<gG, 256, 0, stream>>>(Bb0, Bb1, Bb2, Bb3, Wb2, b2, F0, 1, gpart);
    k_bnredfin<<<128, 128, 0, stream>>>(gpart, g2, be2, ss);
    k_bncvt_pl<<<gCvt, 256, 0, stream>>>(F0, ss, Bb0);

    // ---- layer 3 ----
    k_prop_pl<<<gPP, 256, 0, stream>>>(Bb0, nullptr, rowptr, edg, perm, Bb1);
    k_prop_pl<<<gPP, 256, 0, stream>>>(Bb1, Bb0, rowptr, edg, perm, Bb2);
    k_prop_pl<<<gPP, 256, 0, stream>>>(Bb2, Bb1, rowptr, edg, perm, Bb3);
    k_gemmM<<<gG, 256, 0, stream>>>(Bb0, Bb1, Bb2, Bb3, Wb3, b3, F0, 2, gpart);
    k_bnredfin<<<128, 128, 0, stream>>>(gpart, g3, be3, ss);
    k_bncvt_pl<<<gCvt, 256, 0, stream>>>(F0, ss, Bb0);

    // ---- layer 4 ----
    k_prop_pl<<<gPP, 256, 0, stream>>>(Bb0, nullptr, rowptr, edg, perm, Bb1);
    k_prop_pl<<<gPP, 256, 0, stream>>>(Bb1, Bb0, rowptr, edg, perm, Bb2);
    k_prop_pl<<<gPP, 256, 0, stream>>>(Bb2, Bb1, rowptr, edg, perm, Bb3);
    k_gemmM<<<gG, 256, 0, stream>>>(Bb0, Bb1, Bb2, Bb3, Wb4, b4, F0, 0, nullptr);
    k_l2norm<<<gL2, 256, 0, stream>>>(F0, outp);

    (void)n_in; (void)in_sizes; (void)out_size; (void)ws_size;
}

// Round 9
// 617.035 us; speedup vs baseline: 1.4337x; 1.4337x over previous
//
#include <hip/hip_runtime.h>
#include <hip/hip_fp16.h>

#define NN 50000
#define NE 800000
#define HD 128
#define NSL 128          // edge slices
#define SLE (NE / NSL)   // 6250 edges per slice
#define PW  12500        // packed words per chunk (2 bins/word, 25000 bins/chunk)

typedef __attribute__((ext_vector_type(8))) short short8;
typedef __attribute__((ext_vector_type(4))) float f32x4;
typedef __attribute__((ext_vector_type(4))) unsigned u32x4;

__device__ inline unsigned bf2pack(float lo, float hi) {
    unsigned a = __float_as_uint(lo); a = (a + 0x7fffu + ((a >> 16) & 1u)) >> 16;
    unsigned b = __float_as_uint(hi); b = (b + 0x7fffu + ((b >> 16) & 1u)) >> 16;
    return a | (b << 16);
}

// packed edge: low 16 = src node, high 16 = fp16 weight
__device__ inline float edgw(unsigned p) {
    return __half2float(__ushort_as_half((unsigned short)(p >> 16)));
}

// ---------------------------------------------------------------------------
// Graph prep (atomic-free)
// ---------------------------------------------------------------------------
__global__ __launch_bounds__(256) void k_hist(const int* __restrict__ ei,
                                              unsigned* __restrict__ phist) {
    __shared__ unsigned hist[PW];  // 50 KB
    int b = blockIdx.x;
    int a = b >> 8;
    int s = (b & 255) >> 1;
    int c = b & 1;
    int tid = threadIdx.x;
    for (int i = tid; i < PW; i += 256) hist[i] = 0u;
    __syncthreads();
    const int* arr = ei + a * NE + s * SLE;
    int lo = c * 25000;
    for (int i = tid; i < SLE; i += 256) {
        int v = arr[i] - lo;
        if ((unsigned)v < 25000u)
            atomicAdd(&hist[v >> 1], 1u << ((v & 1) * 16));
    }
    __syncthreads();
    unsigned* dst = phist + (size_t)b * PW;
    for (int i = tid; i < PW; i += 256) dst[i] = hist[i];
}

__global__ __launch_bounds__(256) void k_hreduce(const unsigned* __restrict__ phist,
                                                 float* __restrict__ dinv,
                                                 int* __restrict__ cnt,
                                                 unsigned* __restrict__ pre) {
    int idx = blockIdx.x * 256 + threadIdx.x;
    if (idx >= 50000) return;
    int a = idx / 25000;
    int gw = idx % 25000;
    int c = gw / PW;
    int w = gw % PW;
    unsigned accLo = 0, accHi = 0;
    for (int s = 0; s < NSL; s++) {
        unsigned p = phist[(size_t)(((a * NSL + s) * 2 + c)) * PW + w];
        if (a == 1) pre[(size_t)s * 25000 + gw] = accLo | (accHi << 16);
        accLo += p & 0xffffu;
        accHi += p >> 16;
    }
    int b0 = c * 25000 + 2 * w;
    if (a == 0) {
        dinv[b0]     = accLo ? rsqrtf((float)accLo) : 0.0f;
        dinv[b0 + 1] = accHi ? rsqrtf((float)accHi) : 0.0f;
    } else {
        cnt[b0]     = (int)accLo;
        cnt[b0 + 1] = (int)accHi;
    }
}

__global__ __launch_bounds__(1024) void k_scan1(const int* __restrict__ cnt,
                                                int* __restrict__ rowptr,
                                                int* __restrict__ bsum) {
    __shared__ int s[1024];
    int tid = threadIdx.x;
    int gid = blockIdx.x * 1024 + tid;
    int v = (gid < NN) ? cnt[gid] : 0;
    s[tid] = v;
    __syncthreads();
    for (int off = 1; off < 1024; off <<= 1) {
        int t = 0;
        if (tid >= off) t = s[tid - off];
        __syncthreads();
        s[tid] += t;
        __syncthreads();
    }
    if (gid < NN) rowptr[gid] = s[tid] - v;
    if (tid == 1023) bsum[blockIdx.x] = s[1023];
}

__global__ void k_scan2(const int* __restrict__ bsum, int* __restrict__ boff,
                        int nb, int* __restrict__ rowptr) {
    if (threadIdx.x == 0 && blockIdx.x == 0) {
        int acc = 0;
        for (int i = 0; i < nb; i++) { boff[i] = acc; acc += bsum[i]; }
        rowptr[NN] = acc;
    }
}

__global__ void k_scan3(int* __restrict__ rowptr, const int* __restrict__ boff) {
    int i = blockIdx.x * 256 + threadIdx.x;
    if (i < NN) rowptr[i] += boff[i >> 10];
}

__global__ __launch_bounds__(256) void k_fill2(const int* __restrict__ ei,
                                               const float* __restrict__ dinv,
                                               const int* __restrict__ rowptr,
                                               const unsigned* __restrict__ pre,
                                               unsigned* __restrict__ edg) {
    __shared__ unsigned rank[PW];  // 50 KB
    int b = blockIdx.x;
    int s = b >> 1;
    int c = b & 1;
    int tid = threadIdx.x;
    for (int i = tid; i < PW; i += 256) rank[i] = 0u;
    __syncthreads();
    int lo = c * 25000;
    const unsigned* preS = pre + (size_t)s * 25000 + c * PW;
    for (int i = tid; i < SLE; i += 256) {
        int e = s * SLE + i;
        int d = ei[NE + e];
        int v = d - lo;
        if ((unsigned)v < 25000u) {
            int src = ei[e];
            int w = v >> 1;
            int sh = (v & 1) * 16;
            unsigned r = atomicAdd(&rank[w], 1u << sh);
            r = (r >> sh) & 0xffffu;
            unsigned pw = (preS[w] >> sh) & 0xffffu;
            int pos = rowptr[d] + (int)pw + (int)r;
            unsigned short hw = __half_as_ushort(__float2half(-dinv[src] * dinv[d]));
            edg[pos] = (unsigned)src | ((unsigned)hw << 16);
        }
    }
}

// ---------------------------------------------------------------------------
// Propagation dim-3 (fp32, layer 1 only)
// ---------------------------------------------------------------------------
__global__ void k_prop3(const float* __restrict__ h, const float* __restrict__ sub,
                        const int* __restrict__ rowptr, const unsigned* __restrict__ edg,
                        float* __restrict__ out) {
    int node = blockIdx.x * 256 + threadIdx.x;
    if (node >= NN) return;
    int e0 = rowptr[node], e1 = rowptr[node + 1];
    float a0 = 0.f, a1 = 0.f, a2 = 0.f;
    for (int e = e0; e < e1; e++) {
        unsigned p = edg[e];
        int s = p & 0xffffu;
        float v = edgw(p);
        a0 += v * h[s * 3 + 0];
        a1 += v * h[s * 3 + 1];
        a2 += v * h[s * 3 + 2];
    }
    if (sub) {
        a0 = 2.f * a0 - sub[node * 3 + 0];
        a1 = 2.f * a1 - sub[node * 3 + 1];
        a2 = 2.f * a2 - sub[node * 3 + 2];
    }
    out[node * 3 + 0] = a0;
    out[node * 3 + 1] = a1;
    out[node * 3 + 2] = a2;
}

// ---------------------------------------------------------------------------
// Propagation dim-128, feature-planar bf16 [plane 0..3][node][32].
// XCD-pinned chunks; 4-byte packed edges (u16 src | fp16 w); 8-edge unroll:
// each of a node's 4 lanes loads uint2 (2 edges), shfl-broadcast -> 8 gathers
// in flight per step (2x MLP vs R7). Edge loads cached (no NT); sub/out NT.
// ---------------------------------------------------------------------------
#define ACC8(acc, u, v)                                               \
    acc[0] = fmaf(v, __uint_as_float(u[0] << 16), acc[0]);            \
    acc[1] = fmaf(v, __uint_as_float(u[0] & 0xffff0000u), acc[1]);    \
    acc[2] = fmaf(v, __uint_as_float(u[1] << 16), acc[2]);            \
    acc[3] = fmaf(v, __uint_as_float(u[1] & 0xffff0000u), acc[3]);    \
    acc[4] = fmaf(v, __uint_as_float(u[2] << 16), acc[4]);            \
    acc[5] = fmaf(v, __uint_as_float(u[2] & 0xffff0000u), acc[5]);    \
    acc[6] = fmaf(v, __uint_as_float(u[3] << 16), acc[6]);            \
    acc[7] = fmaf(v, __uint_as_float(u[3] & 0xffff0000u), acc[7]);

__global__ __launch_bounds__(256) void k_prop_pl(
        const unsigned short* __restrict__ h, const unsigned short* __restrict__ sub,
        const int* __restrict__ rowptr, const unsigned* __restrict__ edg,
        unsigned short* __restrict__ out) {
    int B = blockIdx.x;
    int xcd = B & 7;
    int c = xcd >> 1;        // chunk pinned to XCD pair
    int half = xcd & 1;      // node-range half
    int g = B >> 3;          // 0..391
    int n = (half * 392 + g) * 64 + (threadIdx.x >> 2);
    if (n >= NN) return;
    int lane4 = threadIdx.x & 3;
    int sl = lane4 * 8;                       // ushort slice offset
    int base = (threadIdx.x & 63) & ~3;       // node's first lane in wave
    const unsigned short* hp = h + (size_t)c * (NN * 32);
    int e0 = rowptr[n], e1 = rowptr[n + 1];
    float a[8] = {0, 0, 0, 0, 0, 0, 0, 0};
    float b[8] = {0, 0, 0, 0, 0, 0, 0, 0};
    int e = e0;
    for (; e + 8 <= e1; e += 8) {
        uint2 pp = *(const uint2*)(edg + e + lane4 * 2);  // 2 packed edges
        unsigned q0 = __shfl(pp.x, base + 0, 64);
        unsigned q1 = __shfl(pp.y, base + 0, 64);
        unsigned q2 = __shfl(pp.x, base + 1, 64);
        unsigned q3 = __shfl(pp.y, base + 1, 64);
        unsigned q4 = __shfl(pp.x, base + 2, 64);
        unsigned q5 = __shfl(pp.y, base + 2, 64);
        unsigned q6 = __shfl(pp.x, base + 3, 64);
        unsigned q7 = __shfl(pp.y, base + 3, 64);
        u32x4 u0 = *(const u32x4*)(hp + (q0 & 0xffffu) * 32 + sl);
        u32x4 u1 = *(const u32x4*)(hp + (q1 & 0xffffu) * 32 + sl);
        u32x4 u2 = *(const u32x4*)(hp + (q2 & 0xffffu) * 32 + sl);
        u32x4 u3 = *(const u32x4*)(hp + (q3 & 0xffffu) * 32 + sl);
        u32x4 u4 = *(const u32x4*)(hp + (q4 & 0xffffu) * 32 + sl);
        u32x4 u5 = *(const u32x4*)(hp + (q5 & 0xffffu) * 32 + sl);
        u32x4 u6 = *(const u32x4*)(hp + (q6 & 0xffffu) * 32 + sl);
        u32x4 u7 = *(const u32x4*)(hp + (q7 & 0xffffu) * 32 + sl);
        float v0 = edgw(q0), v1 = edgw(q1), v2 = edgw(q2), v3 = edgw(q3);
        float v4 = edgw(q4), v5 = edgw(q5), v6 = edgw(q6), v7 = edgw(q7);
        ACC8(a, u0, v0)
        ACC8(b, u1, v1)
        ACC8(a, u2, v2)
        ACC8(b, u3, v3)
        ACC8(a, u4, v4)
        ACC8(b, u5, v5)
        ACC8(a, u6, v6)
        ACC8(b, u7, v7)
    }
    for (; e < e1; e++) {
        unsigned p = edg[e];
        u32x4 u = *(const u32x4*)(hp + (p & 0xffffu) * 32 + sl);
        float v = edgw(p);
        ACC8(a, u, v)
    }
    float r[8];
    #pragma unroll
    for (int q = 0; q < 8; q++) r[q] = a[q] + b[q];
    if (sub) {
        u32x4 su = __builtin_nontemporal_load(
            (const u32x4*)(sub + (size_t)c * (NN * 32) + n * 32 + sl));
        float s[8];
        s[0] = __uint_as_float(su[0] << 16); s[1] = __uint_as_float(su[0] & 0xffff0000u);
        s[2] = __uint_as_float(su[1] << 16); s[3] = __uint_as_float(su[1] & 0xffff0000u);
        s[4] = __uint_as_float(su[2] << 16); s[5] = __uint_as_float(su[2] & 0xffff0000u);
        s[6] = __uint_as_float(su[3] << 16); s[7] = __uint_as_float(su[3] & 0xffff0000u);
        #pragma unroll
        for (int q = 0; q < 8; q++) r[q] = 2.f * r[q] - s[q];
    }
    u32x4 o;
    o[0] = bf2pack(r[0], r[1]);
    o[1] = bf2pack(r[2], r[3]);
    o[2] = bf2pack(r[4], r[5]);
    o[3] = bf2pack(r[6], r[7]);
    __builtin_nontemporal_store(o, (u32x4*)(out + (size_t)c * (NN * 32) + n * 32 + sl));
}

// ---------------------------------------------------------------------------
// W swizzle fp32 -> bf16 B-fragment order for all three 128x128 weights.
// ---------------------------------------------------------------------------
__global__ void k_wconv_all(const float* __restrict__ W2, const float* __restrict__ W3,
                            const float* __restrict__ W4, unsigned short* __restrict__ Wb) {
    int gidx = blockIdx.x * 256 + threadIdx.x;  // 0..196607
    int which = gidx >> 16;
    int idx = gidx & 65535;
    const float* W = which == 0 ? W2 : (which == 1 ? W3 : W4);
    int slot = idx >> 9;
    int lane = (idx >> 3) & 63;
    int j = idx & 7;
    int wg = slot >> 4;
    int t = slot & 15;
    int w = wg >> 1;
    int g = wg & 1;
    int k = t * 32 + (lane >> 4) * 8 + j;
    int col = w * 32 + g * 16 + (lane & 15);
    unsigned u = __float_as_uint(W[k * HD + col]);
    Wb[which * 65536 + idx] = (unsigned short)((u + 0x7fffu + ((u >> 16) & 1u)) >> 16);
}

// ---------------------------------------------------------------------------
// MFMA GEMM. A staged per 16-row tile into LDS (fragment order); B register-
// resident. Fused BN partials written NON-ATOMICALLY to gpart[col][512].
// ---------------------------------------------------------------------------
__global__ __launch_bounds__(256) void k_gemmM(
        const unsigned short* __restrict__ A0, const unsigned short* __restrict__ A1,
        const unsigned short* __restrict__ A2, const unsigned short* __restrict__ A3,
        const unsigned short* __restrict__ Wb, const float* __restrict__ bias,
        float* __restrict__ outF, int act, float* __restrict__ gpart) {
    __shared__ unsigned short Asm[16 * 64 * 8];  // 16 KB
    const int tid = threadIdx.x;
    const int w = tid >> 6;
    const int lane = tid & 63;
    const int l15 = lane & 15;
    const int quad = lane >> 4;

    short8 Bf[16][2];
    #pragma unroll
    for (int t = 0; t < 16; t++) {
        #pragma unroll
        for (int g = 0; g < 2; g++) {
            int slot = (w * 2 + g) * 16 + t;
            Bf[t][g] = *(const short8*)(Wb + slot * 512 + lane * 8);
        }
    }
    float bcol[2];
    bcol[0] = bias[w * 32 + l15];
    bcol[1] = bias[w * 32 + 16 + l15];

    const unsigned short* Ap[4] = {A0, A1, A2, A3};
    float bnP[2] = {0.f, 0.f}, bnQ[2] = {0.f, 0.f};

    for (int tile = blockIdx.x; tile < NN / 16; tile += gridDim.x) {
        int r0 = tile * 16;
        __syncthreads();
        #pragma unroll
        for (int i = 0; i < 4; i++) {
            int idx = i * 256 + tid;          // 0..1023
            int s = idx >> 6;                 // frag slot 0..15
            int ln = idx & 63;
            const unsigned short* src = Ap[s >> 2] + (size_t)(s & 3) * (NN * 32)
                                        + (r0 + (ln & 15)) * 32 + (ln >> 4) * 8;
            *(uint4*)&Asm[idx * 8] = *(const uint4*)src;
        }
        __syncthreads();
        f32x4 acc0 = {0.f, 0.f, 0.f, 0.f};
        f32x4 acc1 = {0.f, 0.f, 0.f, 0.f};
        #pragma unroll
        for (int s = 0; s < 16; s++) {
            short8 af = *(const short8*)&Asm[(s * 64 + lane) * 8];
            acc0 = __builtin_amdgcn_mfma_f32_16x16x32_bf16(af, Bf[s][0], acc0, 0, 0, 0);
            acc1 = __builtin_amdgcn_mfma_f32_16x16x32_bf16(af, Bf[s][1], acc1, 0, 0, 0);
        }
        #pragma unroll
        for (int reg = 0; reg < 4; reg++) {
            int row = r0 + quad * 4 + reg;
            float v0 = acc0[reg] + bcol[0];
            float v1 = acc1[reg] + bcol[1];
            if (act == 1) {
                v0 = v0 > 0.f ? v0 : 0.01f * v0;
                v1 = v1 > 0.f ? v1 : 0.01f * v1;
            } else if (act == 2) {
                v0 = v0 > 0.f ? v0 : 0.f;
                v1 = v1 > 0.f ? v1 : 0.f;
            }
            outF[row * HD + w * 32 + l15] = v0;
            outF[row * HD + w * 32 + 16 + l15] = v1;
            bnP[0] += v0; bnQ[0] += v0 * v0;
            bnP[1] += v1; bnQ[1] += v1 * v1;
        }
    }
    if (gpart) {
        #pragma unroll
        for (int g = 0; g < 2; g++) {
            float p = bnP[g], q = bnQ[g];
            p += __shfl_xor(p, 16); p += __shfl_xor(p, 32);
            q += __shfl_xor(q, 16); q += __shfl_xor(q, 32);
            if (quad == 0) {
                int col = w * 32 + g * 16 + l15;
                gpart[col * 512 + blockIdx.x] = p;
                gpart[(128 + col) * 512 + blockIdx.x] = q;
            }
        }
    }
}

// ---------------------------------------------------------------------------
// Layer-1 GEMM: [N,3] x4 Cheb terms @ W1[4][3][128] + b, leaky relu -> fp32
// ---------------------------------------------------------------------------
__global__ __launch_bounds__(256) void k_gemm1(
        const float* __restrict__ T0, const float* __restrict__ T1,
        const float* __restrict__ T2, const float* __restrict__ T3,
        const float* __restrict__ W, const float* __restrict__ bias,
        float* __restrict__ out) {
    __shared__ float Ws[12 * 128];
    __shared__ float tx[2][12];
    int t = threadIdx.x;
    for (int i = t; i < 12 * 128; i += 256) Ws[i] = W[i];
    int idx = blockIdx.x * 256 + t;
    int node = idx >> 7;
    int f = idx & 127;
    int localn = t >> 7;
    const float* Ts[4] = {T0, T1, T2, T3};
    if (f < 12 && node < NN) {
        tx[localn][f] = Ts[f / 3][node * 3 + (f % 3)];
    }
    __syncthreads();
    if (node < NN) {
        float acc = bias[f];
        #pragma unroll
        for (int c = 0; c < 12; c++) acc = fmaf(tx[localn][c], Ws[c * 128 + f], acc);
        acc = acc > 0.f ? acc : 0.01f * acc;
        out[node * HD + f] = acc;
    }
}

// ---------------------------------------------------------------------------
// BatchNorm: non-atomic two-stage reduction (stage 2 fused with finalize)
// ---------------------------------------------------------------------------
__global__ __launch_bounds__(256) void k_bnstats2(const float* __restrict__ h,
                                                  float* __restrict__ gpart) {
    __shared__ float red[512];
    int b = blockIdx.x;                 // 0..511
    int f = threadIdx.x & 127;
    int half = threadIdx.x >> 7;
    int r0 = b * 98 + half;
    int r1 = b * 98 + 98;
    if (r1 > NN) r1 = NN;
    float s = 0.f, q = 0.f;
    for (int r = r0; r < r1; r += 2) {
        float v = __builtin_nontemporal_load(h + r * HD + f);
        s += v;
        q += v * v;
    }
    red[threadIdx.x] = s;
    red[256 + threadIdx.x] = q;
    __syncthreads();
    if (threadIdx.x < 128) {
        gpart[f * 512 + b] = red[threadIdx.x] + red[threadIdx.x + 128];
        gpart[(128 + f) * 512 + b] = red[256 + threadIdx.x] + red[384 + threadIdx.x];
    }
}

__global__ __launch_bounds__(128) void k_bnredfin(const float* __restrict__ gpart,
                                                  const float* __restrict__ g,
                                                  const float* __restrict__ be,
                                                  float* __restrict__ ss) {
    __shared__ float sm[2];
    int f = blockIdx.x;            // 0..127
    int wave = threadIdx.x >> 6;   // 0: sum, 1: sumsq
    int lane = threadIdx.x & 63;
    const float* src = gpart + (size_t)(f + wave * 128) * 512;
    float s = 0.f;
    #pragma unroll
    for (int i = 0; i < 8; i++) s += src[i * 64 + lane];
    #pragma unroll
    for (int off = 32; off > 0; off >>= 1) s += __shfl_xor(s, off);
    if (lane == 0) sm[wave] = s;
    __syncthreads();
    if (threadIdx.x == 0) {
        float mean = sm[0] * (1.0f / NN);
        float var = sm[1] * (1.0f / NN) - mean * mean;
        float sc = g[f] * rsqrtf(var + 1e-5f);
        ss[f] = sc;
        ss[128 + f] = be[f] - mean * sc;
    }
}

// BN apply on fp32 row-major src -> bf16 feature-planar out
__global__ void k_bncvt_pl(const float* __restrict__ h, const float* __restrict__ ss,
                           unsigned short* __restrict__ out) {
    int idx = blockIdx.x * 256 + threadIdx.x;  // over NN*16 chunks of 8 feats
    if (idx < NN * 16) {
        int n = idx >> 4;
        int p = (idx >> 2) & 3;
        int q = idx & 3;
        const float4* hf = (const float4*)h;
        float4 v0 = hf[n * 32 + p * 8 + q * 2];
        float4 v1 = hf[n * 32 + p * 8 + q * 2 + 1];
        const float4* s4 = (const float4*)ss;
        float4 c0 = s4[p * 8 + q * 2];
        float4 c1 = s4[p * 8 + q * 2 + 1];
        float4 d0 = s4[32 + p * 8 + q * 2];
        float4 d1 = s4[32 + p * 8 + q * 2 + 1];
        v0.x = fmaf(v0.x, c0.x, d0.x); v0.y = fmaf(v0.y, c0.y, d0.y);
        v0.z = fmaf(v0.z, c0.z, d0.z); v0.w = fmaf(v0.w, c0.w, d0.w);
        v1.x = fmaf(v1.x, c1.x, d1.x); v1.y = fmaf(v1.y, c1.y, d1.y);
        v1.z = fmaf(v1.z, c1.z, d1.z); v1.w = fmaf(v1.w, c1.w, d1.w);
        uint4 o;
        o.x = bf2pack(v0.x, v0.y);
        o.y = bf2pack(v0.z, v0.w);
        o.z = bf2pack(v1.x, v1.y);
        o.w = bf2pack(v1.z, v1.w);
        ((uint4*)out)[(size_t)p * (NN * 4) + n * 4 + q] = o;
    }
}

// ---------------------------------------------------------------------------
// Row L2 normalize -> d_out
// ---------------------------------------------------------------------------
__global__ __launch_bounds__(256) void k_l2norm(const float* __restrict__ h,
                                                float* __restrict__ out) {
    int row = blockIdx.x * 4 + (threadIdx.x >> 6);
    int lane = threadIdx.x & 63;
    if (row >= NN) return;
    float2 v = *(const float2*)(h + row * HD + lane * 2);
    float s = v.x * v.x + v.y * v.y;
    #pragma unroll
    for (int off = 32; off > 0; off >>= 1) s += __shfl_xor(s, off);
    float scale = 1.f / fmaxf(sqrtf(s), 1e-12f);
    *(float2*)(out + row * HD + lane * 2) = make_float2(v.x * scale, v.y * scale);
}

// ---------------------------------------------------------------------------
// Launch
// ---------------------------------------------------------------------------
extern "C" void kernel_launch(void* const* d_in, const int* in_sizes, int n_in,
                              void* d_out, int out_size, void* d_ws, size_t ws_size,
                              hipStream_t stream) {
    const float* x  = (const float*)d_in[0];
    const int*   ei = (const int*)d_in[1];
    const float* W1 = (const float*)d_in[2];
    const float* b1 = (const float*)d_in[3];
    const float* W2 = (const float*)d_in[4];
    const float* b2 = (const float*)d_in[5];
    const float* W3 = (const float*)d_in[6];
    const float* b3 = (const float*)d_in[7];
    const float* W4 = (const float*)d_in[8];
    const float* b4 = (const float*)d_in[9];
    const float* g1 = (const float*)d_in[10];
    const float* be1 = (const float*)d_in[11];
    const float* g2 = (const float*)d_in[12];
    const float* be2 = (const float*)d_in[13];
    const float* g3 = (const float*)d_in[14];
    const float* be3 = (const float*)d_in[15];
    float* outp = (float*)d_out;

    char* base = (char*)d_ws;
    size_t off = 0;
    auto alloc = [&](size_t bytes) -> void* {
        void* p = base + off;
        off += (bytes + 255) & ~(size_t)255;
        return p;
    };
    float* dinv  = (float*)alloc(NN * 4);
    int*   cnt   = (int*)  alloc(NN * 4);
    int*   rowptr= (int*)  alloc((NN + 1) * 4);
    int*   bsum  = (int*)  alloc(64 * 4);
    int*   boff  = (int*)  alloc(64 * 4);
    float* ss    = (float*)alloc(256 * 4);
    float* gpart = (float*)alloc(256 * 512 * 4);
    unsigned short* Wb = (unsigned short*)alloc(3 * 512 * 128 * 2);
    unsigned* edg = (unsigned*)alloc((size_t)NE * 4);
    float* T3a   = (float*)alloc(NN * 3 * 4);
    float* T3b   = (float*)alloc(NN * 3 * 4);
    float* T3c   = (float*)alloc(NN * 3 * 4);
    float* F0    = (float*)alloc((size_t)NN * HD * 4);
    unsigned short* Bb0 = (unsigned short*)alloc((size_t)NN * HD * 2);
    unsigned short* Bb1 = (unsigned short*)alloc((size_t)NN * HD * 2);
    unsigned short* Bb2 = (unsigned short*)alloc((size_t)NN * HD * 2);
    unsigned short* Bb3 = (unsigned short*)alloc((size_t)NN * HD * 2);

    // overlays (consumed before their host slabs are first written):
    unsigned* pre   = (unsigned*)F0;    // 12.8 MB, freed by k_fill2
    unsigned* phist = (unsigned*)Bb0;   // 25.6 MB (Bb0+Bb1), freed by k_hreduce

    const int gN = (NN + 255) / 256;
    const int nb = (NN + 1023) / 1024;

    // ---- graph prep (no global atomics) ----
    k_hist<<<512, 256, 0, stream>>>(ei, phist);
    k_hreduce<<<(50000 + 255) / 256, 256, 0, stream>>>(phist, dinv, cnt, pre);
    k_scan1<<<nb, 1024, 0, stream>>>(cnt, rowptr, bsum);
    k_scan2<<<1, 64, 0, stream>>>(bsum, boff, nb, rowptr);
    k_scan3<<<gN, 256, 0, stream>>>(rowptr, boff);
    k_fill2<<<256, 256, 0, stream>>>(ei, dinv, rowptr, pre, edg);
    k_wconv_all<<<768, 256, 0, stream>>>(W2, W3, W4, Wb);

    const int gPP = 8 * 392;         // XCD-pinned planar prop
    const int gG = 512;              // gemmM grid-stride blocks
    const int gCvt = NN * 16 / 256;  // 3125
    const int gL2 = (NN + 3) / 4;
    unsigned short* Wb2 = Wb;
    unsigned short* Wb3 = Wb + 65536;
    unsigned short* Wb4 = Wb + 131072;

    // ---- layer 1 (in: x [N,3], fp32) ----
    k_prop3<<<gN, 256, 0, stream>>>(x, nullptr, rowptr, edg, T3a);
    k_prop3<<<gN, 256, 0, stream>>>(T3a, x, rowptr, edg, T3b);
    k_prop3<<<gN, 256, 0, stream>>>(T3b, T3a, rowptr, edg, T3c);
    k_gemm1<<<(NN * 128 + 255) / 256, 256, 0, stream>>>(x, T3a, T3b, T3c, W1, b1, F0);
    k_bnstats2<<<512, 256, 0, stream>>>(F0, gpart);
    k_bnredfin<<<128, 128, 0, stream>>>(gpart, g1, be1, ss);
    k_bncvt_pl<<<gCvt, 256, 0, stream>>>(F0, ss, Bb0);

    // ---- layer 2 ----
    k_prop_pl<<<gPP, 256, 0, stream>>>(Bb0, nullptr, rowptr, edg, Bb1);
    k_prop_pl<<<gPP, 256, 0, stream>>>(Bb1, Bb0, rowptr, edg, Bb2);
    k_prop_pl<<<gPP, 256, 0, stream>>>(Bb2, Bb1, rowptr, edg, Bb3);
    k_gemmM<<<gG, 256, 0, stream>>>(Bb0, Bb1, Bb2, Bb3, Wb2, b2, F0, 1, gpart);
    k_bnredfin<<<128, 128, 0, stream>>>(gpart, g2, be2, ss);
    k_bncvt_pl<<<gCvt, 256, 0, stream>>>(F0, ss, Bb0);

    // ---- layer 3 ----
    k_prop_pl<<<gPP, 256, 0, stream>>>(Bb0, nullptr, rowptr, edg, Bb1);
    k_prop_pl<<<gPP, 256, 0, stream>>>(Bb1, Bb0, rowptr, edg, Bb2);
    k_prop_pl<<<gPP, 256, 0, stream>>>(Bb2, Bb1, rowptr, edg, Bb3);
    k_gemmM<<<gG, 256, 0, stream>>>(Bb0, Bb1, Bb2, Bb3, Wb3, b3, F0, 2, gpart);
    k_bnredfin<<<128, 128, 0, stream>>>(gpart, g3, be3, ss);
    k_bncvt_pl<<<gCvt, 256, 0, stream>>>(F0, ss, Bb0);

    // ---- layer 4 ----
    k_prop_pl<<<gPP, 256, 0, stream>>>(Bb0, nullptr, rowptr, edg, Bb1);
    k_prop_pl<<<gPP, 256, 0, stream>>>(Bb1, Bb0, rowptr, edg, Bb2);
    k_prop_pl<<<gPP, 256, 0, stream>>>(Bb2, Bb1, rowptr, edg, Bb3);
    k_gemmM<<<gG, 256, 0, stream>>>(Bb0, Bb1, Bb2, Bb3, Wb4, b4, F0, 0, nullptr);
    k_l2norm<<<gL2, 256, 0, stream>>>(F0, outp);

    (void)n_in; (void)in_sizes; (void)out_size; (void)ws_size;
}